// Round 5
// baseline (465.742 us; speedup 1.0000x reference)
//
#include <hip/hip_runtime.h>
#include <hip/hip_bf16.h>

// Problem dims: B=16, N=1024, E=d_head=128, H=8; M = 16384 rows
typedef __bf16 bf16x8 __attribute__((ext_vector_type(8)));
typedef _Float16 f16x4 __attribute__((ext_vector_type(4)));
typedef float f32x4 __attribute__((ext_vector_type(4)));

__device__ __forceinline__ unsigned short f2bf(float f) {
  union { __hip_bfloat16 h; unsigned short u; } cv;
  cv.h = __float2bfloat16(f);
  return cv.u;
}
__device__ __forceinline__ unsigned short f2h(float f) {
  union { _Float16 h; unsigned short u; } cv;
  cv.h = (_Float16)f;
  return cv.u;
}

__device__ __forceinline__ bf16x8 ld_frag(const unsigned short* p) {
  bf16x8 v;
  __builtin_memcpy(&v, __builtin_assume_aligned(p, 16), 16);
  return v;
}
__device__ __forceinline__ f16x4 ld_h4(const unsigned short* p) {
  f16x4 v;
  __builtin_memcpy(&v, __builtin_assume_aligned(p, 8), 8);
  return v;
}
__device__ __forceinline__ uint4 ld16(const unsigned short* p) {
  uint4 v;
  __builtin_memcpy(&v, __builtin_assume_aligned(p, 16), 16);
  return v;
}
__device__ __forceinline__ void st16(unsigned short* p, uint4 v) {
  __builtin_memcpy(__builtin_assume_aligned(p, 16), &v, 16);
}
// async global->LDS DMA, 16 B per lane; lds dest must be wave-uniform base
__device__ __forceinline__ void dma16(const unsigned short* g, unsigned short* l) {
  __builtin_amdgcn_global_load_lds((const __attribute__((address_space(1))) void*)g,
                                   (__attribute__((address_space(3))) void*)l, 16, 0, 0);
}

// ---------------- LayerNorm + cast to bf16 -----------------
__global__ __launch_bounds__(256) void ln_kernel(const float* __restrict__ x,
                                                 const float* __restrict__ w,
                                                 const float* __restrict__ b,
                                                 unsigned short* __restrict__ xn) {
  int wave = threadIdx.x >> 6;
  int lane = threadIdx.x & 63;
  int row = blockIdx.x * 4 + wave;
  const float* xr = x + (size_t)row * 128;
  float2 v = *reinterpret_cast<const float2*>(xr + lane * 2);
  float s1 = v.x + v.y;
  float s2 = v.x * v.x + v.y * v.y;
#pragma unroll
  for (int off = 32; off > 0; off >>= 1) {
    s1 += __shfl_xor(s1, off, 64);
    s2 += __shfl_xor(s2, off, 64);
  }
  float mu = s1 * (1.0f / 128.0f);
  float var = s2 * (1.0f / 128.0f) - mu * mu;
  float rstd = rsqrtf(var + 1e-5f);
  float a0 = (v.x - mu) * rstd * w[lane * 2] + b[lane * 2];
  float a1 = (v.y - mu) * rstd * w[lane * 2 + 1] + b[lane * 2 + 1];
  unsigned int pk = (unsigned int)f2bf(a0) | ((unsigned int)f2bf(a1) << 16);
  *reinterpret_cast<unsigned int*>(xn + (size_t)row * 128 + lane * 2) = pk;
}

// ---------------- transpose + cast fp32[R][C] -> bf16[C][R] -----------------
__global__ __launch_bounds__(256) void tcast_kernel(const float* __restrict__ in,
                                                    unsigned short* __restrict__ out,
                                                    int R, int C) {
  __shared__ float tile[32][33];
  int tx = threadIdx.x & 31, ty = threadIdx.x >> 5;
  int c0 = blockIdx.x * 32, r0 = blockIdx.y * 32;
#pragma unroll
  for (int k = 0; k < 4; k++)
    tile[ty + 8 * k][tx] = in[(size_t)(r0 + ty + 8 * k) * C + c0 + tx];
  __syncthreads();
#pragma unroll
  for (int k = 0; k < 4; k++)
    out[(size_t)(c0 + ty + 8 * k) * R + r0 + tx] = f2bf(tile[tx][ty + 8 * k]);
}

// ---------------- QKV GEMM, 128x128 tile, BK=64 x2 ----------------
// Q,K cols (0..2047) -> qk[16384][2048] bf16; V cols -> Vt[bh][d][n] fp16
__global__ __launch_bounds__(256) void qkv_gemm(const unsigned short* __restrict__ A,
                                                const unsigned short* __restrict__ Bt,
                                                unsigned short* __restrict__ qk,
                                                unsigned short* __restrict__ Vt) {
  __shared__ unsigned short Al[128 * 72];
  __shared__ unsigned short Bl[128 * 72];
  int t = threadIdx.x;
  int i0 = blockIdx.x * 128, c0 = blockIdx.y * 128;
  int lg = t & 7, rr = t >> 3;  // granule 0..7, row 0..31
  int w = t >> 6, lane = t & 63, l15 = lane & 15, quad = lane >> 4;
  int wy = (w >> 1) * 64, wx = (w & 1) * 64;
  const f32x4 fz = {0.f, 0.f, 0.f, 0.f};
  f32x4 acc[4][4];
#pragma unroll
  for (int i = 0; i < 4; i++)
#pragma unroll
    for (int j = 0; j < 4; j++) acc[i][j] = fz;

#pragma unroll
  for (int kt = 0; kt < 2; kt++) {
    int k0 = kt * 64;
    uint4 areg[4], breg[4];
#pragma unroll
    for (int p = 0; p < 4; p++)
      areg[p] = ld16(&A[(size_t)(i0 + rr + 32 * p) * 128 + k0 + lg * 8]);
#pragma unroll
    for (int p = 0; p < 4; p++)
      breg[p] = ld16(&Bt[(size_t)(c0 + rr + 32 * p) * 128 + k0 + lg * 8]);
    __syncthreads();
#pragma unroll
    for (int p = 0; p < 4; p++) st16(&Al[(rr + 32 * p) * 72 + lg * 8], areg[p]);
#pragma unroll
    for (int p = 0; p < 4; p++) st16(&Bl[(rr + 32 * p) * 72 + lg * 8], breg[p]);
    __syncthreads();
#pragma unroll
    for (int ks = 0; ks < 2; ks++) {
      bf16x8 af[4], bfr[4];
#pragma unroll
      for (int i = 0; i < 4; i++)
        af[i] = ld_frag(&Al[(wy + 16 * i + l15) * 72 + 32 * ks + quad * 8]);
#pragma unroll
      for (int j = 0; j < 4; j++)
        bfr[j] = ld_frag(&Bl[(wx + 16 * j + l15) * 72 + 32 * ks + quad * 8]);
#pragma unroll
      for (int i = 0; i < 4; i++)
#pragma unroll
        for (int j = 0; j < 4; j++)
          acc[i][j] = __builtin_amdgcn_mfma_f32_16x16x32_bf16(af[i], bfr[j], acc[i][j], 0, 0, 0);
    }
  }
  if (blockIdx.y < 16) {
#pragma unroll
    for (int i = 0; i < 4; i++)
#pragma unroll
      for (int j = 0; j < 4; j++)
#pragma unroll
        for (int r = 0; r < 4; r++) {
          int row = i0 + wy + 16 * i + quad * 4 + r;
          int col = c0 + wx + 16 * j + l15;
          qk[(size_t)row * 2048 + col] = f2bf(acc[i][j][r]);
        }
  } else {
    int vc0 = (blockIdx.y - 16) * 128;
#pragma unroll
    for (int i = 0; i < 4; i++)
#pragma unroll
      for (int j = 0; j < 4; j++) {
        int vcol = vc0 + wx + 16 * j + l15;   // 0..1023
        int hh = vcol >> 7, dd = vcol & 127;
        int row0 = i0 + wy + 16 * i + quad * 4;
        int bb = row0 >> 10, nn = row0 & 1023;
        ushort4 pk;
        pk.x = f2h(acc[i][j][0]); pk.y = f2h(acc[i][j][1]);
        pk.z = f2h(acc[i][j][2]); pk.w = f2h(acc[i][j][3]);
        *reinterpret_cast<ushort4*>(Vt + (size_t)(bb * 8 + hh) * 131072 +
                                    (size_t)dd * 1024 + nn) = pk;
      }
  }
}

// ---------------- Flash attention: S^T trick + DMA-staged K/V ---------------
// block = (b,h, 256-row Q tile); 4 waves x 64 rows (4 groups of 16).
// S^T = mfma(K, Q): lane holds P[qrow=l15][kcol=quad*4+r] == A-frag of
// 16x16x16 MFMA -> P feeds PV straight from registers (no LDS round-trip).
// K/V staged by global_load_lds with XOR-granule swizzle (conflict-free,
// zero staging VGPRs).
__global__ __launch_bounds__(256, 2) void attn_kernel(const unsigned short* __restrict__ qk,
                                                      const unsigned short* __restrict__ Vt,
                                                      const float* __restrict__ scale,
                                                      unsigned short* __restrict__ aout) {
  __shared__ __align__(16) unsigned short Kl[64 * 128];  // [kcol][d], granule-swizzled
  __shared__ __align__(16) unsigned short Vl[128 * 64];  // [d][tok], granule-swizzled
  int t = threadIdx.x;
  int idx = blockIdx.x;
  // same-bh q-tiles at blockIdx stride 128 (=0 mod 8) -> same XCD slot
  int bh = idx & 127, qt = idx >> 7;
  int b = bh >> 3, h = bh & 7;
  int q0 = qt * 256;
  float sc = scale[h];
  int w = t >> 6, lane = t & 63, l15 = lane & 15, quad = lane >> 4;

  // Q fragments (B-operand layout: n=l15=qrow, k=quad*8+j), 4 groups of 16
  bf16x8 qf[4][4];
  {
    const unsigned short* qb = qk + (size_t)(b * 1024) * 2048 + h * 128;
#pragma unroll
    for (int g = 0; g < 4; g++) {
      const unsigned short* qp = qb + (size_t)(q0 + 64 * w + 16 * g + l15) * 2048;
#pragma unroll
      for (int ks = 0; ks < 4; ks++) qf[g][ks] = ld_frag(qp + 32 * ks + quad * 8);
    }
  }
  const f32x4 fz = {0.f, 0.f, 0.f, 0.f};
  f32x4 o[4][8];
#pragma unroll
  for (int g = 0; g < 4; g++)
#pragma unroll
    for (int i = 0; i < 8; i++) o[g][i] = fz;
  float plsum[4] = {0.f, 0.f, 0.f, 0.f};

  const unsigned short* kbase = qk + (size_t)(b * 1024) * 2048 + 1024 + h * 128;
  const unsigned short* vbase = Vt + (size_t)bh * 131072;

  // DMA lane mappings (4 K-chunks + 4 V-chunks per wave, 1 KB each)
  int koff[4], voff[4];
#pragma unroll
  for (int i = 0; i < 4; i++) {
    int c = w * 4 + i;
    int krow = c * 4 + (lane >> 4);                    // 0..63 (kcol)
    int kg = ((lane & 15) ^ (krow & 7)) * 8;           // logical 16B granule *8 shorts
    koff[i] = krow * 2048 + kg;
    int vrow = c * 8 + (lane >> 3);                    // 0..127 (d)
    int vg = ((lane & 7) ^ ((vrow >> 1) & 7)) * 8;
    voff[i] = vrow * 1024 + vg;
  }

  for (int kt = 0; kt < 16; kt++) {
    int k0 = kt * 64;
    __syncthreads();  // all waves done reading previous tile
#pragma unroll
    for (int i = 0; i < 4; i++) {
      dma16(kbase + (size_t)k0 * 2048 + koff[i], &Kl[(w * 4 + i) * 512]);
      dma16(vbase + voff[i] + k0, &Vl[(w * 4 + i) * 512]);
    }
    __syncthreads();  // vmcnt drained -> staged data visible

#pragma unroll
    for (int ct = 0; ct < 4; ct++) {
      // S^T tile: A = K (m=kcol), B = Q (n=qrow)
      f32x4 acc[4] = {fz, fz, fz, fz};
#pragma unroll
      for (int ks = 0; ks < 4; ks++) {
        bf16x8 kf = ld_frag(&Kl[(16 * ct + l15) * 128 + ((4 * ks + quad) ^ (l15 & 7)) * 8]);
#pragma unroll
        for (int g = 0; g < 4; g++)
          acc[g] = __builtin_amdgcn_mfma_f32_16x16x32_bf16(kf, qf[g][ks], acc[g], 0, 0, 0);
      }
      // exp + diag-mask + pack into fp16 A-frags for 16x16x16 PV
      f16x4 pa[4];
#pragma unroll
      for (int g = 0; g < 4; g++) {
        bool dj = (q0 + 64 * w + 16 * g) == (k0 + 16 * ct);
#pragma unroll
        for (int r = 0; r < 4; r++) {
          float p = __expf(acc[g][r] * sc);
          if (dj && (quad * 4 + r) == l15) p = 0.f;
          plsum[g] += p;
          pa[g][r] = (_Float16)p;
        }
      }
      // O += P_ct * V_ct  (K=16 MFMA; vf: B[k=quad*4+j][n=l15])
#pragma unroll
      for (int c8 = 0; c8 < 8; c8++) {
        f16x4 vf = ld_h4(&Vl[(16 * c8 + l15) * 64 + ((4 * ct + quad) ^ (l15 & 14)) * 4]);
#pragma unroll
        for (int g = 0; g < 4; g++)
          o[g][c8] = __builtin_amdgcn_mfma_f32_16x16x16f16(pa[g], vf, o[g][c8], 0, 0, 0);
      }
    }
  }

  // epilogue: plsum[g] holds partial over this lane's kcols for qrow=16g+l15.
  // Sum across quads, then redistribute to C-layout rows (quad*4+r).
#pragma unroll
  for (int g = 0; g < 4; g++) {
    float s = plsum[g];
    s += __shfl_xor(s, 16, 64);
    s += __shfl_xor(s, 32, 64);
#pragma unroll
    for (int r = 0; r < 4; r++) {
      float rs = __shfl(s, (lane & 48) + quad * 4 + r, 64);
      float rl = 1.0f / rs;
      int row = b * 1024 + q0 + 64 * w + 16 * g + quad * 4 + r;
#pragma unroll
      for (int c8 = 0; c8 < 8; c8++) {
        int col = h * 128 + 16 * c8 + l15;
        aout[(size_t)row * 1024 + col] = f2bf(o[g][c8][r] * rl);
      }
    }
  }
}

// ---------------- output projection: out = aout @ w_proj + b_proj (fp32) ----
// 64-row x 64-col blocks (512 total -> 2/CU), BK=128 x 8
__global__ __launch_bounds__(256) void proj_gemm(const unsigned short* __restrict__ A,
                                                 const unsigned short* __restrict__ Bt,
                                                 const float* __restrict__ bias,
                                                 float* __restrict__ out) {
  __shared__ unsigned short Al[64 * 136];
  __shared__ unsigned short Bl[64 * 136];
  int t = threadIdx.x;
  int i0 = blockIdx.x * 64, c0 = blockIdx.y * 64;
  int w = t >> 6, lane = t & 63, l15 = lane & 15, quad = lane >> 4;
  int wy = (w >> 1) * 32, wx = (w & 1) * 32;
  const f32x4 fz = {0.f, 0.f, 0.f, 0.f};
  f32x4 acc[2][2];
#pragma unroll
  for (int i = 0; i < 2; i++)
#pragma unroll
    for (int j = 0; j < 2; j++) acc[i][j] = fz;
  int l = t & 15, rr = t >> 4;
  for (int kb = 0; kb < 8; kb++) {
    int k0 = kb * 128;
    uint4 areg[4], breg[4];
#pragma unroll
    for (int p = 0; p < 4; p++)
      areg[p] = ld16(&A[(size_t)(i0 + rr + 16 * p) * 1024 + k0 + l * 8]);
#pragma unroll
    for (int p = 0; p < 4; p++)
      breg[p] = ld16(&Bt[(size_t)(c0 + rr + 16 * p) * 1024 + k0 + l * 8]);
    __syncthreads();
#pragma unroll
    for (int p = 0; p < 4; p++) st16(&Al[(rr + 16 * p) * 136 + l * 8], areg[p]);
#pragma unroll
    for (int p = 0; p < 4; p++) st16(&Bl[(rr + 16 * p) * 136 + l * 8], breg[p]);
    __syncthreads();
#pragma unroll
    for (int ks = 0; ks < 4; ks++) {
      bf16x8 af[2], bfr[2];
#pragma unroll
      for (int i = 0; i < 2; i++)
        af[i] = ld_frag(&Al[(wy + 16 * i + l15) * 136 + 32 * ks + quad * 8]);
#pragma unroll
      for (int j = 0; j < 2; j++)
        bfr[j] = ld_frag(&Bl[(wx + 16 * j + l15) * 136 + 32 * ks + quad * 8]);
#pragma unroll
      for (int i = 0; i < 2; i++)
#pragma unroll
        for (int j = 0; j < 2; j++)
          acc[i][j] = __builtin_amdgcn_mfma_f32_16x16x32_bf16(af[i], bfr[j], acc[i][j], 0, 0, 0);
    }
  }
#pragma unroll
  for (int i = 0; i < 2; i++)
#pragma unroll
    for (int j = 0; j < 2; j++) {
      int col = c0 + wx + 16 * j + l15;
      float bv = bias[col];
#pragma unroll
      for (int r = 0; r < 4; r++) {
        int row = i0 + wy + 16 * i + quad * 4 + r;
        out[(size_t)row * 128 + col] = acc[i][j][r] + bv;
      }
    }
}

extern "C" void kernel_launch(void* const* d_in, const int* in_sizes, int n_in,
                              void* d_out, int out_size, void* d_ws, size_t ws_size,
                              hipStream_t stream) {
  const float* x      = (const float*)d_in[0];
  const float* ln_w   = (const float*)d_in[1];
  const float* ln_b   = (const float*)d_in[2];
  const float* w_qkv  = (const float*)d_in[3];
  const float* scale  = (const float*)d_in[4];
  const float* w_proj = (const float*)d_in[5];
  const float* b_proj = (const float*)d_in[6];
  float* out = (float*)d_out;

  char* ws = (char*)d_ws;
  unsigned short* xn     = (unsigned short*)(ws);               // 4 MB
  unsigned short* wqkvT  = (unsigned short*)(ws + 4194304);     // 768 KB
  unsigned short* wprojT = (unsigned short*)(ws + 4980736);     // 256 KB
  unsigned short* qk     = (unsigned short*)(ws + 5242880);     // 64 MB [16384][2048] bf16
  unsigned short* Vt     = (unsigned short*)(ws + 72351744);    // 32 MB [128][128][1024] fp16
  unsigned short* aout   = (unsigned short*)(ws + 105906176);   // 32 MB bf16
  // total ws use: ~139 MB

  ln_kernel<<<dim3(4096), dim3(256), 0, stream>>>(x, ln_w, ln_b, xn);
  tcast_kernel<<<dim3(96, 4), dim3(256), 0, stream>>>(w_qkv, wqkvT, 128, 3072);
  tcast_kernel<<<dim3(4, 32), dim3(256), 0, stream>>>(w_proj, wprojT, 1024, 128);
  qkv_gemm<<<dim3(128, 24), dim3(256), 0, stream>>>(xn, wqkvT, qk, Vt);
  attn_kernel<<<dim3(512), dim3(256), 0, stream>>>(qk, Vt, scale, aout);
  proj_gemm<<<dim3(256, 2), dim3(256), 0, stream>>>(aout, wprojT, b_proj, out);
}

// Round 6
// 250.777 us; speedup vs baseline: 1.8572x; 1.8572x over previous
//
#include <hip/hip_runtime.h>
#include <hip/hip_bf16.h>

// Problem dims: B=16, N=1024, E=d_head=128, H=8; M = 16384 rows
typedef __bf16 bf16x8 __attribute__((ext_vector_type(8)));
typedef _Float16 f16x4 __attribute__((ext_vector_type(4)));
typedef float f32x4 __attribute__((ext_vector_type(4)));

__device__ __forceinline__ unsigned short f2bf(float f) {
  union { __hip_bfloat16 h; unsigned short u; } cv;
  cv.h = __float2bfloat16(f);
  return cv.u;
}
__device__ __forceinline__ unsigned short f2h(float f) {
  union { _Float16 h; unsigned short u; } cv;
  cv.h = (_Float16)f;
  return cv.u;
}

__device__ __forceinline__ bf16x8 ld_frag(const unsigned short* p) {
  bf16x8 v;
  __builtin_memcpy(&v, __builtin_assume_aligned(p, 16), 16);
  return v;
}
__device__ __forceinline__ f16x4 ld_h4(const unsigned short* p) {
  f16x4 v;
  __builtin_memcpy(&v, __builtin_assume_aligned(p, 8), 8);
  return v;
}
__device__ __forceinline__ uint4 ld16(const unsigned short* p) {
  uint4 v;
  __builtin_memcpy(&v, __builtin_assume_aligned(p, 16), 16);
  return v;
}
__device__ __forceinline__ void st16(unsigned short* p, uint4 v) {
  __builtin_memcpy(__builtin_assume_aligned(p, 16), &v, 16);
}
// async global->LDS DMA, 16 B per lane; lds dest is wave-uniform base + lane*16
__device__ __forceinline__ void dma16(const unsigned short* g, unsigned short* l) {
  __builtin_amdgcn_global_load_lds((const __attribute__((address_space(1))) void*)g,
                                   (__attribute__((address_space(3))) void*)l, 16, 0, 0);
}

// ---------------- LayerNorm + cast to bf16 -----------------
__global__ __launch_bounds__(256) void ln_kernel(const float* __restrict__ x,
                                                 const float* __restrict__ w,
                                                 const float* __restrict__ b,
                                                 unsigned short* __restrict__ xn) {
  int wave = threadIdx.x >> 6;
  int lane = threadIdx.x & 63;
  int row = blockIdx.x * 4 + wave;
  const float* xr = x + (size_t)row * 128;
  float2 v = *reinterpret_cast<const float2*>(xr + lane * 2);
  float s1 = v.x + v.y;
  float s2 = v.x * v.x + v.y * v.y;
#pragma unroll
  for (int off = 32; off > 0; off >>= 1) {
    s1 += __shfl_xor(s1, off, 64);
    s2 += __shfl_xor(s2, off, 64);
  }
  float mu = s1 * (1.0f / 128.0f);
  float var = s2 * (1.0f / 128.0f) - mu * mu;
  float rstd = rsqrtf(var + 1e-5f);
  float a0 = (v.x - mu) * rstd * w[lane * 2] + b[lane * 2];
  float a1 = (v.y - mu) * rstd * w[lane * 2 + 1] + b[lane * 2 + 1];
  unsigned int pk = (unsigned int)f2bf(a0) | ((unsigned int)f2bf(a1) << 16);
  *reinterpret_cast<unsigned int*>(xn + (size_t)row * 128 + lane * 2) = pk;
}

// ---------------- transpose + cast fp32[R][C] -> bf16[C][R] -----------------
__global__ __launch_bounds__(256) void tcast_kernel(const float* __restrict__ in,
                                                    unsigned short* __restrict__ out,
                                                    int R, int C) {
  __shared__ float tile[32][33];
  int tx = threadIdx.x & 31, ty = threadIdx.x >> 5;
  int c0 = blockIdx.x * 32, r0 = blockIdx.y * 32;
#pragma unroll
  for (int k = 0; k < 4; k++)
    tile[ty + 8 * k][tx] = in[(size_t)(r0 + ty + 8 * k) * C + c0 + tx];
  __syncthreads();
#pragma unroll
  for (int k = 0; k < 4; k++)
    out[(size_t)(c0 + ty + 8 * k) * R + r0 + tx] = f2bf(tile[tx][ty + 8 * k]);
}

// ---------------- QKV GEMM, 128x128 tile, BK=64 x2 ----------------
// Q,K cols (0..2047) -> qk[16384][2048] bf16; V cols -> Vt[bh][d][n] fp16
__global__ __launch_bounds__(256) void qkv_gemm(const unsigned short* __restrict__ A,
                                                const unsigned short* __restrict__ Bt,
                                                unsigned short* __restrict__ qk,
                                                unsigned short* __restrict__ Vt) {
  __shared__ unsigned short Al[128 * 72];
  __shared__ unsigned short Bl[128 * 72];
  int t = threadIdx.x;
  int i0 = blockIdx.x * 128, c0 = blockIdx.y * 128;
  int lg = t & 7, rr = t >> 3;  // granule 0..7, row 0..31
  int w = t >> 6, lane = t & 63, l15 = lane & 15, quad = lane >> 4;
  int wy = (w >> 1) * 64, wx = (w & 1) * 64;
  const f32x4 fz = {0.f, 0.f, 0.f, 0.f};
  f32x4 acc[4][4];
#pragma unroll
  for (int i = 0; i < 4; i++)
#pragma unroll
    for (int j = 0; j < 4; j++) acc[i][j] = fz;

#pragma unroll
  for (int kt = 0; kt < 2; kt++) {
    int k0 = kt * 64;
    uint4 areg[4], breg[4];
#pragma unroll
    for (int p = 0; p < 4; p++)
      areg[p] = ld16(&A[(size_t)(i0 + rr + 32 * p) * 128 + k0 + lg * 8]);
#pragma unroll
    for (int p = 0; p < 4; p++)
      breg[p] = ld16(&Bt[(size_t)(c0 + rr + 32 * p) * 128 + k0 + lg * 8]);
    __syncthreads();
#pragma unroll
    for (int p = 0; p < 4; p++) st16(&Al[(rr + 32 * p) * 72 + lg * 8], areg[p]);
#pragma unroll
    for (int p = 0; p < 4; p++) st16(&Bl[(rr + 32 * p) * 72 + lg * 8], breg[p]);
    __syncthreads();
#pragma unroll
    for (int ks = 0; ks < 2; ks++) {
      bf16x8 af[4], bfr[4];
#pragma unroll
      for (int i = 0; i < 4; i++)
        af[i] = ld_frag(&Al[(wy + 16 * i + l15) * 72 + 32 * ks + quad * 8]);
#pragma unroll
      for (int j = 0; j < 4; j++)
        bfr[j] = ld_frag(&Bl[(wx + 16 * j + l15) * 72 + 32 * ks + quad * 8]);
#pragma unroll
      for (int i = 0; i < 4; i++)
#pragma unroll
        for (int j = 0; j < 4; j++)
          acc[i][j] = __builtin_amdgcn_mfma_f32_16x16x32_bf16(af[i], bfr[j], acc[i][j], 0, 0, 0);
    }
  }
  if (blockIdx.y < 16) {
#pragma unroll
    for (int i = 0; i < 4; i++)
#pragma unroll
      for (int j = 0; j < 4; j++)
#pragma unroll
        for (int r = 0; r < 4; r++) {
          int row = i0 + wy + 16 * i + quad * 4 + r;
          int col = c0 + wx + 16 * j + l15;
          qk[(size_t)row * 2048 + col] = f2bf(acc[i][j][r]);
        }
  } else {
    int vc0 = (blockIdx.y - 16) * 128;
#pragma unroll
    for (int i = 0; i < 4; i++)
#pragma unroll
      for (int j = 0; j < 4; j++) {
        int vcol = vc0 + wx + 16 * j + l15;   // 0..1023
        int hh = vcol >> 7, dd = vcol & 127;
        int row0 = i0 + wy + 16 * i + quad * 4;
        int bb = row0 >> 10, nn = row0 & 1023;
        ushort4 pk;
        pk.x = f2h(acc[i][j][0]); pk.y = f2h(acc[i][j][1]);
        pk.z = f2h(acc[i][j][2]); pk.w = f2h(acc[i][j][3]);
        *reinterpret_cast<ushort4*>(Vt + (size_t)(bb * 8 + hh) * 131072 +
                                    (size_t)dd * 1024 + nn) = pk;
      }
  }
}

// ---------------- Flash attention: S^T trick, 32 Q-rows/wave, DMA K/V -------
// block = (b,h, 128-row Q tile); 4 waves x 32 rows (2 groups of 16).
// S^T = mfma(K, Q): lane holds P[qrow=l15][kcol=quad*4+r] == A-frag of the
// 16x16x16 f16 MFMA -> P feeds PV straight from registers (no LDS round-trip).
// K/V staged via global_load_lds with XOR-granule swizzle; fits registers at
// 32 rows/wave (o=64 + qf=32 unified regs), unlike the 64-row variant (R4/R5
// spill disaster: 424/928 MB scratch WRITE_SIZE).
__global__ __launch_bounds__(256, 3) void attn_kernel(const unsigned short* __restrict__ qk,
                                                      const unsigned short* __restrict__ Vt,
                                                      const float* __restrict__ scale,
                                                      unsigned short* __restrict__ aout) {
  __shared__ __align__(16) unsigned short Kl[64 * 128];  // [kcol][d], granule-swizzled
  __shared__ __align__(16) unsigned short Vl[128 * 64];  // [d][tok], granule-swizzled
  int t = threadIdx.x;
  int idx = blockIdx.x;
  // same-bh q-tiles at blockIdx stride 128 (=0 mod 8) -> same XCD slot
  int bh = idx & 127, qt = idx >> 7;
  int b = bh >> 3, h = bh & 7;
  int q0 = qt * 128;
  float sc = scale[h];
  int w = t >> 6, lane = t & 63, l15 = lane & 15, quad = lane >> 4;

  // Q fragments (B-operand layout: n=l15=qrow, k=quad*8+j), 2 groups of 16
  bf16x8 qf[2][4];
  {
    const unsigned short* qb = qk + (size_t)(b * 1024) * 2048 + h * 128;
#pragma unroll
    for (int g = 0; g < 2; g++) {
      const unsigned short* qp = qb + (size_t)(q0 + 32 * w + 16 * g + l15) * 2048;
#pragma unroll
      for (int ks = 0; ks < 4; ks++) qf[g][ks] = ld_frag(qp + 32 * ks + quad * 8);
    }
  }
  const f32x4 fz = {0.f, 0.f, 0.f, 0.f};
  f32x4 o[2][8];
#pragma unroll
  for (int g = 0; g < 2; g++)
#pragma unroll
    for (int i = 0; i < 8; i++) o[g][i] = fz;
  float plsum[2] = {0.f, 0.f};

  const unsigned short* kbase = qk + (size_t)(b * 1024) * 2048 + 1024 + h * 128;
  const unsigned short* vbase = Vt + (size_t)bh * 131072;

  // DMA lane mappings (4 K-chunks + 4 V-chunks per wave, 1 KB each)
  int koff[4], voff[4];
#pragma unroll
  for (int i = 0; i < 4; i++) {
    int c = w * 4 + i;
    int krow = c * 4 + (lane >> 4);                    // 0..63 (kcol)
    int kg = ((lane & 15) ^ (krow & 7)) * 8;           // 16B granule * 8 shorts
    koff[i] = krow * 2048 + kg;
    int vrow = c * 8 + (lane >> 3);                    // 0..127 (d)
    int vg = ((lane & 7) ^ ((vrow >> 1) & 7)) * 8;
    voff[i] = vrow * 1024 + vg;
  }

  for (int kt = 0; kt < 16; kt++) {
    int k0 = kt * 64;
    __syncthreads();  // all waves done reading previous tile
#pragma unroll
    for (int i = 0; i < 4; i++) {
      dma16(kbase + (size_t)k0 * 2048 + koff[i], &Kl[(w * 4 + i) * 512]);
      dma16(vbase + voff[i] + k0, &Vl[(w * 4 + i) * 512]);
    }
    __syncthreads();  // vmcnt drained -> staged data visible

#pragma unroll
    for (int ct = 0; ct < 4; ct++) {
      // S^T tile: A = K (m=kcol), B = Q (n=qrow)
      f32x4 acc[2] = {fz, fz};
#pragma unroll
      for (int ks = 0; ks < 4; ks++) {
        bf16x8 kf = ld_frag(&Kl[(16 * ct + l15) * 128 + ((4 * ks + quad) ^ (l15 & 7)) * 8]);
#pragma unroll
        for (int g = 0; g < 2; g++)
          acc[g] = __builtin_amdgcn_mfma_f32_16x16x32_bf16(kf, qf[g][ks], acc[g], 0, 0, 0);
      }
      // exp + diag-mask + pack into fp16 A-frags for 16x16x16 PV
      f16x4 pa[2];
#pragma unroll
      for (int g = 0; g < 2; g++) {
        bool dj = (q0 + 32 * w + 16 * g) == (k0 + 16 * ct);
#pragma unroll
        for (int r = 0; r < 4; r++) {
          float p = __expf(acc[g][r] * sc);
          if (dj && (quad * 4 + r) == l15) p = 0.f;
          plsum[g] += p;
          pa[g][r] = (_Float16)p;
        }
      }
      // O += P_ct * V_ct  (K=16 f16 MFMA; vf: B[k=quad*4+j][n=l15])
#pragma unroll
      for (int c8 = 0; c8 < 8; c8++) {
        f16x4 vf = ld_h4(&Vl[(16 * c8 + l15) * 64 + ((4 * ct + quad) ^ (l15 & 14)) * 4]);
#pragma unroll
        for (int g = 0; g < 2; g++)
          o[g][c8] = __builtin_amdgcn_mfma_f32_16x16x16f16(pa[g], vf, o[g][c8], 0, 0, 0);
      }
    }
  }

  // epilogue: plsum[g] = partial over this lane's kcols for qrow=16g+l15.
  // Sum across quads, then redistribute to C-layout rows (quad*4+r).
#pragma unroll
  for (int g = 0; g < 2; g++) {
    float s = plsum[g];
    s += __shfl_xor(s, 16, 64);
    s += __shfl_xor(s, 32, 64);
#pragma unroll
    for (int r = 0; r < 4; r++) {
      float rs = __shfl(s, (lane & 48) + quad * 4 + r, 64);
      float rl = 1.0f / rs;
      int row = b * 1024 + q0 + 32 * w + 16 * g + quad * 4 + r;
#pragma unroll
      for (int c8 = 0; c8 < 8; c8++) {
        int col = h * 128 + 16 * c8 + l15;
        aout[(size_t)row * 1024 + col] = f2bf(o[g][c8][r] * rl);
      }
    }
  }
}

// ---------------- output projection: out = aout @ w_proj + b_proj (fp32) ----
// 64-row x 64-col blocks (512 total -> 2/CU), BK=128 x 8
__global__ __launch_bounds__(256) void proj_gemm(const unsigned short* __restrict__ A,
                                                 const unsigned short* __restrict__ Bt,
                                                 const float* __restrict__ bias,
                                                 float* __restrict__ out) {
  __shared__ unsigned short Al[64 * 136];
  __shared__ unsigned short Bl[64 * 136];
  int t = threadIdx.x;
  int i0 = blockIdx.x * 64, c0 = blockIdx.y * 64;
  int w = t >> 6, lane = t & 63, l15 = lane & 15, quad = lane >> 4;
  int wy = (w >> 1) * 32, wx = (w & 1) * 32;
  const f32x4 fz = {0.f, 0.f, 0.f, 0.f};
  f32x4 acc[2][2];
#pragma unroll
  for (int i = 0; i < 2; i++)
#pragma unroll
    for (int j = 0; j < 2; j++) acc[i][j] = fz;
  int l = t & 15, rr = t >> 4;
  for (int kb = 0; kb < 8; kb++) {
    int k0 = kb * 128;
    uint4 areg[4], breg[4];
#pragma unroll
    for (int p = 0; p < 4; p++)
      areg[p] = ld16(&A[(size_t)(i0 + rr + 16 * p) * 1024 + k0 + l * 8]);
#pragma unroll
    for (int p = 0; p < 4; p++)
      breg[p] = ld16(&Bt[(size_t)(c0 + rr + 16 * p) * 1024 + k0 + l * 8]);
    __syncthreads();
#pragma unroll
    for (int p = 0; p < 4; p++) st16(&Al[(rr + 16 * p) * 136 + l * 8], areg[p]);
#pragma unroll
    for (int p = 0; p < 4; p++) st16(&Bl[(rr + 16 * p) * 136 + l * 8], breg[p]);
    __syncthreads();
#pragma unroll
    for (int ks = 0; ks < 4; ks++) {
      bf16x8 af[2], bfr[2];
#pragma unroll
      for (int i = 0; i < 2; i++)
        af[i] = ld_frag(&Al[(wy + 16 * i + l15) * 136 + 32 * ks + quad * 8]);
#pragma unroll
      for (int j = 0; j < 2; j++)
        bfr[j] = ld_frag(&Bl[(wx + 16 * j + l15) * 136 + 32 * ks + quad * 8]);
#pragma unroll
      for (int i = 0; i < 2; i++)
#pragma unroll
        for (int j = 0; j < 2; j++)
          acc[i][j] = __builtin_amdgcn_mfma_f32_16x16x32_bf16(af[i], bfr[j], acc[i][j], 0, 0, 0);
    }
  }
#pragma unroll
  for (int i = 0; i < 2; i++)
#pragma unroll
    for (int j = 0; j < 2; j++) {
      int col = c0 + wx + 16 * j + l15;
      float bv = bias[col];
#pragma unroll
      for (int r = 0; r < 4; r++) {
        int row = i0 + wy + 16 * i + quad * 4 + r;
        out[(size_t)row * 128 + col] = acc[i][j][r] + bv;
      }
    }
}

extern "C" void kernel_launch(void* const* d_in, const int* in_sizes, int n_in,
                              void* d_out, int out_size, void* d_ws, size_t ws_size,
                              hipStream_t stream) {
  const float* x      = (const float*)d_in[0];
  const float* ln_w   = (const float*)d_in[1];
  const float* ln_b   = (const float*)d_in[2];
  const float* w_qkv  = (const float*)d_in[3];
  const float* scale  = (const float*)d_in[4];
  const float* w_proj = (const float*)d_in[5];
  const float* b_proj = (const float*)d_in[6];
  float* out = (float*)d_out;

  char* ws = (char*)d_ws;
  unsigned short* xn     = (unsigned short*)(ws);               // 4 MB
  unsigned short* wqkvT  = (unsigned short*)(ws + 4194304);     // 768 KB
  unsigned short* wprojT = (unsigned short*)(ws + 4980736);     // 256 KB
  unsigned short* qk     = (unsigned short*)(ws + 5242880);     // 64 MB [16384][2048] bf16
  unsigned short* Vt     = (unsigned short*)(ws + 72351744);    // 32 MB [128][128][1024] fp16
  unsigned short* aout   = (unsigned short*)(ws + 105906176);   // 32 MB bf16
  // total ws use: ~139 MB

  ln_kernel<<<dim3(4096), dim3(256), 0, stream>>>(x, ln_w, ln_b, xn);
  tcast_kernel<<<dim3(96, 4), dim3(256), 0, stream>>>(w_qkv, wqkvT, 128, 3072);
  tcast_kernel<<<dim3(4, 32), dim3(256), 0, stream>>>(w_proj, wprojT, 1024, 128);
  qkv_gemm<<<dim3(128, 24), dim3(256), 0, stream>>>(xn, wqkvT, qk, Vt);
  attn_kernel<<<dim3(1024), dim3(256), 0, stream>>>(qk, Vt, scale, aout);
  proj_gemm<<<dim3(256, 2), dim3(256), 0, stream>>>(aout, wprojT, b_proj, out);
}

// Round 7
// 207.128 us; speedup vs baseline: 2.2486x; 1.2107x over previous
//
#include <hip/hip_runtime.h>
#include <hip/hip_bf16.h>

// Problem dims: B=16, N=1024, E=d_head=128, H=8; M = 16384 rows
typedef __bf16 bf16x8 __attribute__((ext_vector_type(8)));
typedef _Float16 f16x4 __attribute__((ext_vector_type(4)));
typedef float f32x4 __attribute__((ext_vector_type(4)));

__device__ __forceinline__ unsigned short f2bf(float f) {
  union { __hip_bfloat16 h; unsigned short u; } cv;
  cv.h = __float2bfloat16(f);
  return cv.u;
}
__device__ __forceinline__ unsigned short f2h(float f) {
  union { _Float16 h; unsigned short u; } cv;
  cv.h = (_Float16)f;
  return cv.u;
}

__device__ __forceinline__ bf16x8 ld_frag(const unsigned short* p) {
  bf16x8 v;
  __builtin_memcpy(&v, __builtin_assume_aligned(p, 16), 16);
  return v;
}
__device__ __forceinline__ f16x4 ld_h4(const unsigned short* p) {
  f16x4 v;
  __builtin_memcpy(&v, __builtin_assume_aligned(p, 8), 8);
  return v;
}
__device__ __forceinline__ uint4 ld16(const unsigned short* p) {
  uint4 v;
  __builtin_memcpy(&v, __builtin_assume_aligned(p, 16), 16);
  return v;
}
__device__ __forceinline__ void st16(unsigned short* p, uint4 v) {
  __builtin_memcpy(__builtin_assume_aligned(p, 16), &v, 16);
}
// async global->LDS DMA, 16 B per lane; lds dest is wave-uniform base + lane*16
__device__ __forceinline__ void dma16(const unsigned short* g, unsigned short* l) {
  __builtin_amdgcn_global_load_lds((const __attribute__((address_space(1))) void*)g,
                                   (__attribute__((address_space(3))) void*)l, 16, 0, 0);
}

// ---------------- LayerNorm + cast to bf16 -----------------
__global__ __launch_bounds__(256) void ln_kernel(const float* __restrict__ x,
                                                 const float* __restrict__ w,
                                                 const float* __restrict__ b,
                                                 unsigned short* __restrict__ xn) {
  int wave = threadIdx.x >> 6;
  int lane = threadIdx.x & 63;
  int row = blockIdx.x * 4 + wave;
  const float* xr = x + (size_t)row * 128;
  float2 v = *reinterpret_cast<const float2*>(xr + lane * 2);
  float s1 = v.x + v.y;
  float s2 = v.x * v.x + v.y * v.y;
#pragma unroll
  for (int off = 32; off > 0; off >>= 1) {
    s1 += __shfl_xor(s1, off, 64);
    s2 += __shfl_xor(s2, off, 64);
  }
  float mu = s1 * (1.0f / 128.0f);
  float var = s2 * (1.0f / 128.0f) - mu * mu;
  float rstd = rsqrtf(var + 1e-5f);
  float a0 = (v.x - mu) * rstd * w[lane * 2] + b[lane * 2];
  float a1 = (v.y - mu) * rstd * w[lane * 2 + 1] + b[lane * 2 + 1];
  unsigned int pk = (unsigned int)f2bf(a0) | ((unsigned int)f2bf(a1) << 16);
  *reinterpret_cast<unsigned int*>(xn + (size_t)row * 128 + lane * 2) = pk;
}

// ---------------- transpose + cast fp32[R][C] -> bf16[C][R] -----------------
__global__ __launch_bounds__(256) void tcast_kernel(const float* __restrict__ in,
                                                    unsigned short* __restrict__ out,
                                                    int R, int C) {
  __shared__ float tile[32][33];
  int tx = threadIdx.x & 31, ty = threadIdx.x >> 5;
  int c0 = blockIdx.x * 32, r0 = blockIdx.y * 32;
#pragma unroll
  for (int k = 0; k < 4; k++)
    tile[ty + 8 * k][tx] = in[(size_t)(r0 + ty + 8 * k) * C + c0 + tx];
  __syncthreads();
#pragma unroll
  for (int k = 0; k < 4; k++)
    out[(size_t)(c0 + ty + 8 * k) * R + r0 + tx] = f2bf(tile[tx][ty + 8 * k]);
}

// ---------------- QKV GEMM, 128x128 tile, BK=64 x2 ----------------
// Q cols (0..1023, pre-scaled by scale[h]) and K cols -> qk[16384][2048] bf16;
// V cols -> Vt[bh][d][n] fp16
__global__ __launch_bounds__(256) void qkv_gemm(const unsigned short* __restrict__ A,
                                                const unsigned short* __restrict__ Bt,
                                                const float* __restrict__ scale,
                                                unsigned short* __restrict__ qk,
                                                unsigned short* __restrict__ Vt) {
  __shared__ unsigned short Al[128 * 72];
  __shared__ unsigned short Bl[128 * 72];
  int t = threadIdx.x;
  int i0 = blockIdx.x * 128, c0 = blockIdx.y * 128;
  int lg = t & 7, rr = t >> 3;  // granule 0..7, row 0..31
  int w = t >> 6, lane = t & 63, l15 = lane & 15, quad = lane >> 4;
  int wy = (w >> 1) * 64, wx = (w & 1) * 64;
  const f32x4 fz = {0.f, 0.f, 0.f, 0.f};
  f32x4 acc[4][4];
#pragma unroll
  for (int i = 0; i < 4; i++)
#pragma unroll
    for (int j = 0; j < 4; j++) acc[i][j] = fz;

#pragma unroll
  for (int kt = 0; kt < 2; kt++) {
    int k0 = kt * 64;
    uint4 areg[4], breg[4];
#pragma unroll
    for (int p = 0; p < 4; p++)
      areg[p] = ld16(&A[(size_t)(i0 + rr + 32 * p) * 128 + k0 + lg * 8]);
#pragma unroll
    for (int p = 0; p < 4; p++)
      breg[p] = ld16(&Bt[(size_t)(c0 + rr + 32 * p) * 128 + k0 + lg * 8]);
    __syncthreads();
#pragma unroll
    for (int p = 0; p < 4; p++) st16(&Al[(rr + 32 * p) * 72 + lg * 8], areg[p]);
#pragma unroll
    for (int p = 0; p < 4; p++) st16(&Bl[(rr + 32 * p) * 72 + lg * 8], breg[p]);
    __syncthreads();
#pragma unroll
    for (int ks = 0; ks < 2; ks++) {
      bf16x8 af[4], bfr[4];
#pragma unroll
      for (int i = 0; i < 4; i++)
        af[i] = ld_frag(&Al[(wy + 16 * i + l15) * 72 + 32 * ks + quad * 8]);
#pragma unroll
      for (int j = 0; j < 4; j++)
        bfr[j] = ld_frag(&Bl[(wx + 16 * j + l15) * 72 + 32 * ks + quad * 8]);
#pragma unroll
      for (int i = 0; i < 4; i++)
#pragma unroll
        for (int j = 0; j < 4; j++)
          acc[i][j] = __builtin_amdgcn_mfma_f32_16x16x32_bf16(af[i], bfr[j], acc[i][j], 0, 0, 0);
    }
  }
  if (blockIdx.y < 16) {
    // Q blocks (y<8) carry scale[h] folded in; h == blockIdx.y for y<8
    float qsc = (blockIdx.y < 8) ? scale[blockIdx.y] : 1.0f;
#pragma unroll
    for (int i = 0; i < 4; i++)
#pragma unroll
      for (int j = 0; j < 4; j++)
#pragma unroll
        for (int r = 0; r < 4; r++) {
          int row = i0 + wy + 16 * i + quad * 4 + r;
          int col = c0 + wx + 16 * j + l15;
          qk[(size_t)row * 2048 + col] = f2bf(acc[i][j][r] * qsc);
        }
  } else {
    int vc0 = (blockIdx.y - 16) * 128;
#pragma unroll
    for (int i = 0; i < 4; i++)
#pragma unroll
      for (int j = 0; j < 4; j++) {
        int vcol = vc0 + wx + 16 * j + l15;   // 0..1023
        int hh = vcol >> 7, dd = vcol & 127;
        int row0 = i0 + wy + 16 * i + quad * 4;
        int bb = row0 >> 10, nn = row0 & 1023;
        ushort4 pk;
        pk.x = f2h(acc[i][j][0]); pk.y = f2h(acc[i][j][1]);
        pk.z = f2h(acc[i][j][2]); pk.w = f2h(acc[i][j][3]);
        *reinterpret_cast<ushort4*>(Vt + (size_t)(bb * 8 + hh) * 131072 +
                                    (size_t)dd * 1024 + nn) = pk;
      }
  }
}

// ---------------- Flash attention: S^T + double-buffered DMA K/V ------------
// block = (b,h, 128-row Q tile); 4 waves x 32 rows (2 groups of 16).
// Single barrier per kt: DMA for tile kt+1 issued AFTER the barrier into the
// other buffer; its vmcnt(0) drain happens at the NEXT barrier, a full compute
// phase later -> global latency fully hidden (fix for R6's exposed drain).
__global__ __launch_bounds__(256, 2) void attn_kernel(const unsigned short* __restrict__ qk,
                                                      const unsigned short* __restrict__ Vt,
                                                      unsigned short* __restrict__ aout) {
  __shared__ __align__(16) unsigned short Kl[2][64 * 128];  // [kcol][d], granule-swizzled
  __shared__ __align__(16) unsigned short Vl[2][128 * 64];  // [d][tok], granule-swizzled
  int t = threadIdx.x;
  int idx = blockIdx.x;
  // same-bh q-tiles at blockIdx stride 128 (=0 mod 8) -> same XCD slot
  int bh = idx & 127, qt = idx >> 7;
  int b = bh >> 3, h = bh & 7;
  int q0 = qt * 128;
  int w = t >> 6, lane = t & 63, l15 = lane & 15, quad = lane >> 4;

  // Q fragments (B-operand layout: n=l15=qrow, k=quad*8+j), 2 groups of 16
  bf16x8 qf[2][4];
  {
    const unsigned short* qb = qk + (size_t)(b * 1024) * 2048 + h * 128;
#pragma unroll
    for (int g = 0; g < 2; g++) {
      const unsigned short* qp = qb + (size_t)(q0 + 32 * w + 16 * g + l15) * 2048;
#pragma unroll
      for (int ks = 0; ks < 4; ks++) qf[g][ks] = ld_frag(qp + 32 * ks + quad * 8);
    }
  }
  const f32x4 fz = {0.f, 0.f, 0.f, 0.f};
  f32x4 o[2][8];
#pragma unroll
  for (int g = 0; g < 2; g++)
#pragma unroll
    for (int i = 0; i < 8; i++) o[g][i] = fz;
  float plsum[2] = {0.f, 0.f};

  const unsigned short* kbase = qk + (size_t)(b * 1024) * 2048 + 1024 + h * 128;
  const unsigned short* vbase = Vt + (size_t)bh * 131072;

  // DMA lane mappings (4 K-chunks + 4 V-chunks per wave, 1 KB each)
  int koff[4], voff[4];
#pragma unroll
  for (int i = 0; i < 4; i++) {
    int c = w * 4 + i;
    int krow = c * 4 + (lane >> 4);                    // 0..63 (kcol)
    int kg = ((lane & 15) ^ (krow & 7)) * 8;           // 16B granule * 8 shorts
    koff[i] = krow * 2048 + kg;
    int vrow = c * 8 + (lane >> 3);                    // 0..127 (d)
    int vg = ((lane & 7) ^ ((vrow >> 1) & 7)) * 8;
    voff[i] = vrow * 1024 + vg;
  }

  // preload tile 0 into buffer 0
#pragma unroll
  for (int i = 0; i < 4; i++) {
    dma16(kbase + koff[i], &Kl[0][(w * 4 + i) * 512]);
    dma16(vbase + voff[i], &Vl[0][(w * 4 + i) * 512]);
  }

  for (int kt = 0; kt < 16; kt++) {
    int k0 = kt * 64;
    __syncthreads();  // drains own tile-kt DMAs (issued ~1 compute phase ago)
                      // + all waves done reading buf[~kt] -> safe to overwrite
    {
      int nb = (kt + 1) & 1;
      int kn0 = ((kt + 1) & 15) * 64;
#pragma unroll
      for (int i = 0; i < 4; i++) {
        dma16(kbase + (size_t)kn0 * 2048 + koff[i], &Kl[nb][(w * 4 + i) * 512]);
        dma16(vbase + voff[i] + kn0, &Vl[nb][(w * 4 + i) * 512]);
      }
    }
    const unsigned short* Kc = Kl[kt & 1];
    const unsigned short* Vc = Vl[kt & 1];

#pragma unroll
    for (int ct = 0; ct < 4; ct++) {
      // S^T tile: A = K (m=kcol), B = Q (n=qrow); scale pre-folded into Q
      f32x4 acc[2] = {fz, fz};
#pragma unroll
      for (int ks = 0; ks < 4; ks++) {
        bf16x8 kf = ld_frag(&Kc[(16 * ct + l15) * 128 + ((4 * ks + quad) ^ (l15 & 7)) * 8]);
#pragma unroll
        for (int g = 0; g < 2; g++)
          acc[g] = __builtin_amdgcn_mfma_f32_16x16x32_bf16(kf, qf[g][ks], acc[g], 0, 0, 0);
      }
      // exp + diag-mask (wave-uniform branch) + pack to fp16 A-frags
      f16x4 pa[2];
#pragma unroll
      for (int g = 0; g < 2; g++) {
        if ((q0 + 32 * w + 16 * g) == (k0 + 16 * ct)) {
#pragma unroll
          for (int r = 0; r < 4; r++) {
            float p = ((quad * 4 + r) == l15) ? 0.f : __expf(acc[g][r]);
            plsum[g] += p;
            pa[g][r] = (_Float16)p;
          }
        } else {
#pragma unroll
          for (int r = 0; r < 4; r++) {
            float p = __expf(acc[g][r]);
            plsum[g] += p;
            pa[g][r] = (_Float16)p;
          }
        }
      }
      // O += P_ct * V_ct  (K=16 f16 MFMA; vf: B[k=quad*4+j][n=l15])
#pragma unroll
      for (int c8 = 0; c8 < 8; c8++) {
        f16x4 vf = ld_h4(&Vc[(16 * c8 + l15) * 64 + ((4 * ct + quad) ^ (l15 & 14)) * 4]);
#pragma unroll
        for (int g = 0; g < 2; g++)
          o[g][c8] = __builtin_amdgcn_mfma_f32_16x16x16f16(pa[g], vf, o[g][c8], 0, 0, 0);
      }
    }
  }

  // epilogue: plsum[g] = partial over this lane's kcols for qrow=16g+l15.
  // Sum across quads, then redistribute to C-layout rows (quad*4+r).
#pragma unroll
  for (int g = 0; g < 2; g++) {
    float s = plsum[g];
    s += __shfl_xor(s, 16, 64);
    s += __shfl_xor(s, 32, 64);
#pragma unroll
    for (int r = 0; r < 4; r++) {
      float rs = __shfl(s, (lane & 48) + quad * 4 + r, 64);
      float rl = 1.0f / rs;
      int row = b * 1024 + q0 + 32 * w + 16 * g + quad * 4 + r;
#pragma unroll
      for (int c8 = 0; c8 < 8; c8++) {
        int col = h * 128 + 16 * c8 + l15;
        aout[(size_t)row * 1024 + col] = f2bf(o[g][c8][r] * rl);
      }
    }
  }
}

// ---------------- output projection: out = aout @ w_proj + b_proj (fp32) ----
// 64-row x 64-col blocks (512 total -> 2/CU), BK=128 x 8
__global__ __launch_bounds__(256) void proj_gemm(const unsigned short* __restrict__ A,
                                                 const unsigned short* __restrict__ Bt,
                                                 const float* __restrict__ bias,
                                                 float* __restrict__ out) {
  __shared__ unsigned short Al[64 * 136];
  __shared__ unsigned short Bl[64 * 136];
  int t = threadIdx.x;
  int i0 = blockIdx.x * 64, c0 = blockIdx.y * 64;
  int w = t >> 6, lane = t & 63, l15 = lane & 15, quad = lane >> 4;
  int wy = (w >> 1) * 32, wx = (w & 1) * 32;
  const f32x4 fz = {0.f, 0.f, 0.f, 0.f};
  f32x4 acc[2][2];
#pragma unroll
  for (int i = 0; i < 2; i++)
#pragma unroll
    for (int j = 0; j < 2; j++) acc[i][j] = fz;
  int l = t & 15, rr = t >> 4;
  for (int kb = 0; kb < 8; kb++) {
    int k0 = kb * 128;
    uint4 areg[4], breg[4];
#pragma unroll
    for (int p = 0; p < 4; p++)
      areg[p] = ld16(&A[(size_t)(i0 + rr + 16 * p) * 1024 + k0 + l * 8]);
#pragma unroll
    for (int p = 0; p < 4; p++)
      breg[p] = ld16(&Bt[(size_t)(c0 + rr + 16 * p) * 1024 + k0 + l * 8]);
    __syncthreads();
#pragma unroll
    for (int p = 0; p < 4; p++) st16(&Al[(rr + 16 * p) * 136 + l * 8], areg[p]);
#pragma unroll
    for (int p = 0; p < 4; p++) st16(&Bl[(rr + 16 * p) * 136 + l * 8], breg[p]);
    __syncthreads();
#pragma unroll
    for (int ks = 0; ks < 4; ks++) {
      bf16x8 af[2], bfr[2];
#pragma unroll
      for (int i = 0; i < 2; i++)
        af[i] = ld_frag(&Al[(wy + 16 * i + l15) * 136 + 32 * ks + quad * 8]);
#pragma unroll
      for (int j = 0; j < 2; j++)
        bfr[j] = ld_frag(&Bl[(wx + 16 * j + l15) * 136 + 32 * ks + quad * 8]);
#pragma unroll
      for (int i = 0; i < 2; i++)
#pragma unroll
        for (int j = 0; j < 2; j++)
          acc[i][j] = __builtin_amdgcn_mfma_f32_16x16x32_bf16(af[i], bfr[j], acc[i][j], 0, 0, 0);
    }
  }
#pragma unroll
  for (int i = 0; i < 2; i++)
#pragma unroll
    for (int j = 0; j < 2; j++) {
      int col = c0 + wx + 16 * j + l15;
      float bv = bias[col];
#pragma unroll
      for (int r = 0; r < 4; r++) {
        int row = i0 + wy + 16 * i + quad * 4 + r;
        out[(size_t)row * 128 + col] = acc[i][j][r] + bv;
      }
    }
}

extern "C" void kernel_launch(void* const* d_in, const int* in_sizes, int n_in,
                              void* d_out, int out_size, void* d_ws, size_t ws_size,
                              hipStream_t stream) {
  const float* x      = (const float*)d_in[0];
  const float* ln_w   = (const float*)d_in[1];
  const float* ln_b   = (const float*)d_in[2];
  const float* w_qkv  = (const float*)d_in[3];
  const float* scale  = (const float*)d_in[4];
  const float* w_proj = (const float*)d_in[5];
  const float* b_proj = (const float*)d_in[6];
  float* out = (float*)d_out;

  char* ws = (char*)d_ws;
  unsigned short* xn     = (unsigned short*)(ws);               // 4 MB
  unsigned short* wqkvT  = (unsigned short*)(ws + 4194304);     // 768 KB
  unsigned short* wprojT = (unsigned short*)(ws + 4980736);     // 256 KB
  unsigned short* qk     = (unsigned short*)(ws + 5242880);     // 64 MB [16384][2048] bf16
  unsigned short* Vt     = (unsigned short*)(ws + 72351744);    // 32 MB [128][128][1024] fp16
  unsigned short* aout   = (unsigned short*)(ws + 105906176);   // 32 MB bf16
  // total ws use: ~139 MB

  ln_kernel<<<dim3(4096), dim3(256), 0, stream>>>(x, ln_w, ln_b, xn);
  tcast_kernel<<<dim3(96, 4), dim3(256), 0, stream>>>(w_qkv, wqkvT, 128, 3072);
  tcast_kernel<<<dim3(4, 32), dim3(256), 0, stream>>>(w_proj, wprojT, 1024, 128);
  qkv_gemm<<<dim3(128, 24), dim3(256), 0, stream>>>(xn, wqkvT, scale, qk, Vt);
  attn_kernel<<<dim3(1024), dim3(256), 0, stream>>>(qk, Vt, aout);
  proj_gemm<<<dim3(256, 2), dim3(256), 0, stream>>>(aout, wprojT, b_proj, out);
}